// Round 2
// baseline (709.502 us; speedup 1.0000x reference)
//
#include <hip/hip_runtime.h>

#define NB   32
#define H    1024
#define W    1024
#define BAND 8               // output rows per block
#define NBANDS (H / BAND)    // 128 bands per image
#define ROWS (BAND + 6)      // 14 input rows per block
#define TOPK 200
#define NMS_THRESH 0.1f
#define HI_THRESH  0.999f    // fast-path split; exact fallback preserved
#define CAPH 32              // hi keys per band bucket (E~8)
#define LBL  384             // LDS lo buffer per block (E~167, ~+16 sigma)
#define STAGE_CAP 2048       // hi keys staged in LDS (E~1000); else exact lo path

typedef unsigned long long ull;

__device__ __forceinline__ float4 fmax4(float4 a, float4 b) {
    return make_float4(fmaxf(a.x, b.x), fmaxf(a.y, b.y),
                       fmaxf(a.z, b.z), fmaxf(a.w, b.w));
}

// LDS is time-shared: phase 1 (NMS emit buffers) finishes before the
// winner block's phase 2 (top-k select) touches p2. Union keeps the
// block footprint at ~25.4 KB (2 blocks/CU -> 51 KB/CU, far under 160 KB).
struct P1s { ull lb_lo[LBL]; ull lb_hi[CAPH]; };
struct P2s {
    ull stage[STAGE_CAP];        // 16 KB: all hi keys (common case)
    ull sel[256];                // 2 KB
    unsigned hist[4][256];       // 4 KB wave-private histograms
    unsigned sfx[256];           // 1 KB
    int s_ch[NBANDS];
    int s_cl[NBANDS];
    int s_oh[NBANDS + 1];
};
union SHu { P1s p1; P2s p2; };

// ---------------- Fused: 7x7 NMS + last-block-per-image top-200 ----------
// R1 lesson: fusing phase 2 flipped the RA occupancy heuristic (VGPR 68,
// loads re-sunk, 556 us latency-bound). Fix is to PIN the scheduling
// regime, not restructure:
//   - amdgpu_waves_per_eu(2,2): exact 2 waves/EU -> 256-VGPR budget, no
//     register-minimization motive.
//   - sched_barrier(0) after each 21-load burst: no consumer may be
//     scheduled above the loads, no load below -> 21 outstanding
//     loads/wave by construction.
__global__ __launch_bounds__(256)
__attribute__((amdgpu_waves_per_eu(2, 2)))
void fused_kernel(
    const float* __restrict__ in,
    ull* __restrict__ cand_hi,   // [NB*NBANDS][CAPH]
    ull* __restrict__ cand_lo,   // [NB*NBANDS][capl]
    int* __restrict__ cntl,      // [NB*NBANDS]
    int* __restrict__ cnth,      // [NB*NBANDS], -1 => hi overflow -> lo path
    int* __restrict__ done,      // [NB] arrival counters (memset 0 pre-launch)
    float* __restrict__ out,
    int capl)
{
    __shared__ SHu sh;
    __shared__ int lc_lo, lc_hi;
    __shared__ int s_win, s_ok, s_stop, scnt, s_k;
    __shared__ unsigned s_pref, wsum[4];

    const int img  = blockIdx.y;
    const int band = blockIdx.x;
    const int R0   = band * BAND;
    const char* base = (const char*)(in + ((size_t)img << 20));
    const int t = threadIdx.x;

    if (t == 0) { lc_lo = 0; lc_hi = 0; }

    const int cb  = t << 4;                       // own quad byte offset
    const int cbL = (t == 0)   ? cb : cb - 16;    // clamped left quad
    const int cbR = (t == 255) ? cb : cb + 16;    // clamped right quad

    float4 h[ROWS];   // horizontal 7-max per input row
    float4 c[BAND];   // own centers for output rows (input rows 3..10)

    #pragma unroll
    for (int half = 0; half < 2; half++) {
        const int rb = half * 7;
        float4 oq[7], lq[7], rq[7];
        // ---- burst load: 21 independent loads, zero consumers ----
        #pragma unroll
        for (int r = 0; r < 7; r++) {
            const int ri = min(max(R0 - 3 + rb + r, 0), H - 1);  // exact clamp
            const char* rp = base + ((size_t)ri << 12);
            oq[r] = *(const float4*)(rp + cb);
            lq[r] = *(const float4*)(rp + cbL);
            rq[r] = *(const float4*)(rp + cbR);
        }
        // hard fence: nothing crosses -> all 21 loads issued before any use
        __builtin_amdgcn_sched_barrier(0);
        // ---- consume: horizontal 7-max via prefix/suffix ----
        #pragma unroll
        for (int r = 0; r < 7; r++) {
            float S3 = oq[r].x;
            float S2 = fmaxf(lq[r].w, S3);
            float S1 = fmaxf(lq[r].z, S2);
            float S0 = fmaxf(lq[r].y, S1);
            float P4 = oq[r].y;
            float P5 = fmaxf(P4, oq[r].z);
            float P6 = fmaxf(P5, oq[r].w);
            float P7 = fmaxf(P6, rq[r].x);
            float P8 = fmaxf(P7, rq[r].y);
            float P9 = fmaxf(P8, rq[r].z);
            h[rb + r] = make_float4(fmaxf(S0, P6), fmaxf(S1, P7),
                                    fmaxf(S2, P8), fmaxf(S3, P9));
            const int rr = rb + r;
            if (rr >= 3 && rr < 3 + BAND) c[rr - 3] = oq[r];
        }
    }
    __syncthreads();   // lc_lo/lc_hi init visible before emits

    // ---- Phase B: vertical window + peak emit (static indices) ----
    #pragma unroll
    for (int ro = 0; ro < BAND; ro++) {
        float4 wm = fmax4(fmax4(fmax4(h[ro], h[ro + 1]),
                                fmax4(h[ro + 2], h[ro + 3])),
                          fmax4(fmax4(h[ro + 4], h[ro + 5]), h[ro + 6]));
        float4 ctr = c[ro];
        const int rg = R0 + ro;
        bool p0 = (ctr.x > NMS_THRESH) && (ctr.x == wm.x);
        bool p1 = (ctr.y > NMS_THRESH) && (ctr.y == wm.y);
        bool p2 = (ctr.z > NMS_THRESH) && (ctr.z == wm.z);
        bool p3 = (ctr.w > NMS_THRESH) && (ctr.w == wm.w);
        int cnt = (int)p0 + (int)p1 + (int)p2 + (int)p3;
        if (cnt) {                                // rare per thread-row
            int s = atomicAdd(&lc_lo, cnt);
            unsigned ib = ((unsigned)rg << 10) | ((unsigned)t << 2);
            float cv[4] = {ctr.x, ctr.y, ctr.z, ctr.w};
            bool  pp[4] = {p0, p1, p2, p3};
            #pragma unroll
            for (int j = 0; j < 4; j++) {
                if (pp[j]) {
                    ull key = ((ull)__float_as_uint(cv[j]) << 32) |
                              (ull)(0xFFFFFFFFu - (ib + j));
                    if (s < LBL) sh.p1.lb_lo[s] = key;
                    s++;
                    if (cv[j] > HI_THRESH) {      // ~1/20 of peaks
                        int q = atomicAdd(&lc_hi, 1);
                        if (q < CAPH) sh.p1.lb_hi[q] = key;
                    }
                }
            }
        }
    }

    // ---- flush: coalesced stores to this block's private bucket ----
    __syncthreads();
    const int bkt = img * NBANDS + band;
    const int nl_raw = lc_lo, nh_raw = lc_hi;
    const int nl = min(nl_raw, min(LBL, capl));
    const int nhc = min(nh_raw, CAPH);
    ull* glo = cand_lo + (size_t)bkt * capl;
    for (int i = t; i < nl; i += 256) glo[i] = sh.p1.lb_lo[i];
    ull* ghi = cand_hi + (size_t)bkt * CAPH;
    if (t < nhc) ghi[t] = sh.p1.lb_hi[t];
    if (t == 0) {
        cntl[bkt] = nl;
        cnth[bkt] = (nh_raw > CAPH) ? -1 : nh_raw;   // -1: force exact lo path
    }

    // ---- arrival: device-scope release, 128th block owns this image ----
    __threadfence();           // each thread: make its bucket stores visible
    __syncthreads();
    if (t == 0)
        s_win = (atomicAdd(&done[img], 1) == NBANDS - 1) ? 1 : 0;
    __syncthreads();
    if (!s_win) return;
    __threadfence();           // acquire: invalidate stale L1/L2 lines

    // ================= Phase 2: exact top-200 for this image =============
    const int wv = t >> 6;
    const int boff = img * NBANDS;
    if (t == 0) { s_ok = 1; s_stop = 0; scnt = 0; }
    __syncthreads();
    if (t < NBANDS) {
        int raw = cnth[boff + t];
        sh.p2.s_ch[t] = max(raw, 0);
        sh.p2.s_cl[t] = cntl[boff + t];
        if (raw < 0) s_ok = 0;       // benign race: all writers store 0
    }
    __syncthreads();
    if (t == 0) {
        int a = 0;
        for (int b = 0; b < NBANDS; b++) { sh.p2.s_oh[b] = a; a += sh.p2.s_ch[b]; }
        sh.p2.s_oh[NBANDS] = a;
    }
    __syncthreads();
    const int nh = sh.p2.s_oh[NBANDS];
    // hi path valid iff every non-hi value (<= 0.999) is below every hi value
    // AND all hi keys were captured AND they fit the LDS stage.
    const bool use_hi = (nh >= TOPK) && (nh <= STAGE_CAP) && (s_ok != 0);

    if (use_hi) {
        int b = t >> 1, i0 = t & 1;              // 2 threads per band
        int nb = sh.p2.s_ch[b], ob = sh.p2.s_oh[b];
        const ull* p = cand_hi + (size_t)(boff + b) * CAPH;
        for (int i = i0; i < nb; i += 2) sh.p2.stage[ob + i] = p[i];
    }
    __syncthreads();

    int n_tot = nh;
    if (!use_hi) {
        n_tot = 0;
        for (int b = 0; b < NBANDS; b++) n_tot += sh.p2.s_cl[b];
    }

    unsigned T = 0;   // value-bits threshold
    if (n_tot > TOPK) {
        // Radix-select on value bits, MSB byte first. Early exit the moment
        // the candidate set {vb >= prefix} is <= 256: the bitonic sort on
        // full keys finishes the exact (tie-broken) top-200 from there.
        unsigned prefix = 0, maskhi = 0;
        int kk = TOPK;
        for (int byte = 3; byte >= 0; byte--) {
            #pragma unroll
            for (int w = 0; w < 4; w++) sh.p2.hist[w][t] = 0;
            __syncthreads();
            const int shift = byte * 8;
            if (use_hi) {
                for (int i = t; i < nh; i += 256) {
                    unsigned vb = (unsigned)(sh.p2.stage[i] >> 32);
                    if ((vb & maskhi) == prefix)
                        atomicAdd(&sh.p2.hist[wv][(vb >> shift) & 0xFFu], 1u);
                }
            } else {
                for (int b = 0; b < NBANDS; b++) {
                    int nb = sh.p2.s_cl[b];
                    const ull* p = cand_lo + (size_t)(boff + b) * capl;
                    for (int i = t; i < nb; i += 256) {
                        unsigned vb = (unsigned)(p[i] >> 32);
                        if ((vb & maskhi) == prefix)
                            atomicAdd(&sh.p2.hist[wv][(vb >> shift) & 0xFFu], 1u);
                    }
                }
            }
            __syncthreads();
            // suffix-scan of the 256 bins: wave-shuffle (2 syncs, not 16)
            unsigned v = sh.p2.hist[0][t] + sh.p2.hist[1][t] +
                         sh.p2.hist[2][t] + sh.p2.hist[3][t];
            const int lane = t & 63;
            #pragma unroll
            for (int off = 1; off < 64; off <<= 1) {
                unsigned u = __shfl_down(v, off);
                if (lane + off < 64) v += u;
            }
            if (lane == 0) wsum[wv] = v;
            __syncthreads();
            unsigned add = 0;
            for (int w = wv + 1; w < 4; w++) add += wsum[w];
            unsigned myfx = v + add;             // count(matching, byte >= t)
            sh.p2.sfx[t] = myfx;
            __syncthreads();
            unsigned nxt = (t == 255) ? 0u : sh.p2.sfx[t + 1];
            if (myfx >= (unsigned)kk && nxt < (unsigned)kk) {
                s_pref = prefix | ((unsigned)t << shift);
                s_k = kk - (int)nxt;
                // candidates {vb >= new prefix, low bits 0} = (TOPK-kk) + myfx
                if ((TOPK - kk) + (int)myfx <= 256) s_stop = 1;
            }
            __syncthreads();
            prefix = s_pref;
            kk = s_k;
            maskhi |= (0xFFu << shift);
            if (s_stop) break;
        }
        T = prefix;
    }

    __syncthreads();
    if (use_hi) {
        for (int i = t; i < nh; i += 256) {
            ull k = sh.p2.stage[i];
            if ((unsigned)(k >> 32) >= T) {
                int s = atomicAdd(&scnt, 1);
                if (s < 256) sh.p2.sel[s] = k;
            }
        }
    } else {
        for (int b = 0; b < NBANDS; b++) {
            int nb = sh.p2.s_cl[b];
            const ull* p = cand_lo + (size_t)(boff + b) * capl;
            for (int i = t; i < nb; i += 256) {
                ull k = p[i];
                if ((unsigned)(k >> 32) >= T) {
                    int s = atomicAdd(&scnt, 1);
                    if (s < 256) sh.p2.sel[s] = k;
                }
            }
        }
    }
    __syncthreads();
    const int m = min(scnt, 256);
    if (t >= m) sh.p2.sel[t] = 0ull;
    __syncthreads();

    // bitonic sort 256 keys, descending (full key: value desc, index asc)
    for (int k2 = 2; k2 <= 256; k2 <<= 1) {
        for (int j = k2 >> 1; j > 0; j >>= 1) {
            int ixj = t ^ j;
            if (ixj > t) {
                ull a = sh.p2.sel[t], b = sh.p2.sel[ixj];
                bool descBlock = ((t & k2) == 0);
                bool sw = descBlock ? (a < b) : (a > b);
                if (sw) { sh.p2.sel[t] = b; sh.p2.sel[ixj] = a; }
            }
            __syncthreads();
        }
    }

    // write: coords [NB,TOPK,2] then probs [NB,TOPK], all fp32
    const int meff = min(m, TOPK);
    if (t < TOPK) {
        float prob = 0.0f;
        unsigned row = 0, col = 0;
        if (t < meff) {
            ull key = sh.p2.sel[t];
            prob = __uint_as_float((unsigned)(key >> 32));
            unsigned idx = 0xFFFFFFFFu - (unsigned)(key & 0xFFFFFFFFull);
            row = idx >> 10;
            col = idx & (W - 1);
        }
        size_t cbase = (size_t)img * TOPK * 2 + (size_t)t * 2;
        out[cbase + 0] = (float)row;
        out[cbase + 1] = (float)col;
        out[(size_t)NB * TOPK * 2 + (size_t)img * TOPK + t] = prob;
    }
}

extern "C" void kernel_launch(void* const* d_in, const int* in_sizes, int n_in,
                              void* d_out, int out_size, void* d_ws, size_t ws_size,
                              hipStream_t stream) {
    const float* center_map = (const float*)d_in[0];
    float* out = (float*)d_out;

    // workspace layout:
    //   [0, 16K)          : cntl[4096]
    //   [16K, 32K)        : cnth[4096]
    //   [32K, 32K+128)    : done[32]    (zeroed via tiny memset each launch)
    //   [33K, 33K+1M)     : cand_hi[4096][CAPH]
    //   rest              : cand_lo[4096][capl]
    const int nbkt = NB * NBANDS;   // 4096
    int* cntl = (int*)d_ws;
    int* cnth = (int*)((char*)d_ws + 16384);
    int* done = (int*)((char*)d_ws + 32768);
    ull* cand_hi = (ull*)((char*)d_ws + 32768 + 1024);
    size_t hi_bytes = (size_t)nbkt * CAPH * sizeof(ull);   // 1 MB
    ull* cand_lo = (ull*)((char*)d_ws + 32768 + 1024 + hi_bytes);
    size_t head = 32768 + 1024 + hi_bytes;
    size_t avail = (ws_size > head) ? (ws_size - head) : 0;
    int capl = (int)(avail / (nbkt * sizeof(ull)));
    if (capl > LBL) capl = LBL;
    if (capl < 1) capl = 1;

    hipMemsetAsync(done, 0, NB * sizeof(int), stream);   // 128 B, capture-safe

    dim3 grid(NBANDS, NB);   // 128 x 32 = 4096 blocks
    fused_kernel<<<grid, 256, 0, stream>>>(center_map, cand_hi, cand_lo,
                                           cntl, cnth, done, out, capl);
}

// Round 3
// 207.565 us; speedup vs baseline: 3.4182x; 3.4182x over previous
//
#include <hip/hip_runtime.h>
#include <hip/hip_bf16.h>

#define NB   32
#define H    1024
#define W    1024
#define BAND 8               // output rows per block
#define NBANDS (H / BAND)    // 128 bands per image
#define ROWS (BAND + 6)      // 14 input rows per block
#define TOPK 200
#define NMS_THRESH 0.1f
#define HI_THRESH  0.999f    // fast-path split; exact fallback preserved
#define CAPH 32              // hi keys per band bucket (E~8)
#define LBL  384             // LDS lo buffer per block (E~167, ~+16 sigma)

typedef unsigned long long ull;

__device__ __forceinline__ float4 fmax4(float4 a, float4 b) {
    return make_float4(fmaxf(a.x, b.x), fmaxf(a.y, b.y),
                       fmaxf(a.z, b.z), fmaxf(a.w, b.w));
}

// ---------------- Phase 1: 7x7 NMS, forced-burst loads ----------------
// BYTE-IDENTICAL to the 215.4us-verified kernel. R1/R2 lesson: fusing the
// top-k phase into this kernel flips the pre-RA scheduler's occupancy
// target (VGPR 68/88, loads re-sunk, 556/595us) and no source-level
// attribute (waves_per_eu, sched_barrier) could pin it. Do not append
// code to this kernel.
__global__ __launch_bounds__(256, 2) void peak_kernel(
    const float* __restrict__ in,
    ull* __restrict__ cand_hi,   // [NB*NBANDS][CAPH]
    ull* __restrict__ cand_lo,   // [NB*NBANDS][capl]
    int* __restrict__ cntl,      // [NB*NBANDS]
    int* __restrict__ cnth,      // [NB*NBANDS], -1 => hi overflow -> lo path
    int capl)
{
    __shared__ ull lb_lo[LBL];   // 3 KB
    __shared__ ull lb_hi[CAPH];  // 256 B
    __shared__ int lc_lo, lc_hi;

    const int img  = blockIdx.y;
    const int band = blockIdx.x;
    const int R0   = band * BAND;
    const char* base = (const char*)(in + ((size_t)img << 20));
    const int t = threadIdx.x;

    if (t == 0) { lc_lo = 0; lc_hi = 0; }

    const int cb  = t << 4;                       // own quad byte offset
    const int cbL = (t == 0)   ? cb : cb - 16;    // clamped left quad
    const int cbR = (t == 255) ? cb : cb + 16;    // clamped right quad

    float4 h[ROWS];   // horizontal 7-max per input row
    float4 c[BAND];   // own centers for output rows (input rows 3..10)

    #pragma unroll
    for (int half = 0; half < 2; half++) {
        const int rb = half * 7;
        float4 oq[7], lq[7], rq[7];
        // ---- burst load: 21 independent loads, zero consumers ----
        #pragma unroll
        for (int r = 0; r < 7; r++) {
            const int ri = min(max(R0 - 3 + rb + r, 0), H - 1);  // exact clamp
            const char* rp = base + ((size_t)ri << 12);
            oq[r] = *(const float4*)(rp + cb);
            lq[r] = *(const float4*)(rp + cbL);
            rq[r] = *(const float4*)(rp + cbR);
        }
        // ---- consume: horizontal 7-max via prefix/suffix ----
        #pragma unroll
        for (int r = 0; r < 7; r++) {
            // v0..v9 = lq.y lq.z lq.w oq.x oq.y oq.z oq.w rq.x rq.y rq.z
            float S3 = oq[r].x;
            float S2 = fmaxf(lq[r].w, S3);
            float S1 = fmaxf(lq[r].z, S2);
            float S0 = fmaxf(lq[r].y, S1);
            float P4 = oq[r].y;
            float P5 = fmaxf(P4, oq[r].z);
            float P6 = fmaxf(P5, oq[r].w);
            float P7 = fmaxf(P6, rq[r].x);
            float P8 = fmaxf(P7, rq[r].y);
            float P9 = fmaxf(P8, rq[r].z);
            h[rb + r] = make_float4(fmaxf(S0, P6), fmaxf(S1, P7),
                                    fmaxf(S2, P8), fmaxf(S3, P9));
            const int rr = rb + r;
            if (rr >= 3 && rr < 3 + BAND) c[rr - 3] = oq[r];
        }
    }
    __syncthreads();   // lc_lo/lc_hi init visible before emits

    // ---- Phase B: vertical window + peak emit (static indices) ----
    #pragma unroll
    for (int ro = 0; ro < BAND; ro++) {
        float4 wm = fmax4(fmax4(fmax4(h[ro], h[ro + 1]),
                                fmax4(h[ro + 2], h[ro + 3])),
                          fmax4(fmax4(h[ro + 4], h[ro + 5]), h[ro + 6]));
        float4 ctr = c[ro];
        const int rg = R0 + ro;
        bool p0 = (ctr.x > NMS_THRESH) && (ctr.x == wm.x);
        bool p1 = (ctr.y > NMS_THRESH) && (ctr.y == wm.y);
        bool p2 = (ctr.z > NMS_THRESH) && (ctr.z == wm.z);
        bool p3 = (ctr.w > NMS_THRESH) && (ctr.w == wm.w);
        int cnt = (int)p0 + (int)p1 + (int)p2 + (int)p3;
        if (cnt) {                                // rare per thread-row
            int s = atomicAdd(&lc_lo, cnt);
            unsigned ib = ((unsigned)rg << 10) | ((unsigned)t << 2);
            float cv[4] = {ctr.x, ctr.y, ctr.z, ctr.w};
            bool  pp[4] = {p0, p1, p2, p3};
            #pragma unroll
            for (int j = 0; j < 4; j++) {
                if (pp[j]) {
                    ull key = ((ull)__float_as_uint(cv[j]) << 32) |
                              (ull)(0xFFFFFFFFu - (ib + j));
                    if (s < LBL) lb_lo[s] = key;
                    s++;
                    if (cv[j] > HI_THRESH) {      // ~1/20 of peaks
                        int q = atomicAdd(&lc_hi, 1);
                        if (q < CAPH) lb_hi[q] = key;
                    }
                }
            }
        }
    }

    // ---- flush: coalesced stores to this block's private bucket ----
    __syncthreads();
    const int bkt = img * NBANDS + band;
    const int nl_raw = lc_lo, nh_raw = lc_hi;
    const int nl = min(nl_raw, min(LBL, capl));
    const int nh = min(nh_raw, CAPH);
    ull* glo = cand_lo + (size_t)bkt * capl;
    for (int i = t; i < nl; i += 256) glo[i] = lb_lo[i];
    ull* ghi = cand_hi + (size_t)bkt * CAPH;
    if (t < nh) ghi[t] = lb_hi[t];
    if (t == 0) {
        cntl[bkt] = nl;
        cnth[bkt] = (nh_raw > CAPH) ? -1 : nh_raw;   // -1: force exact lo path
    }
}

// ---------------- Phase 2: per-image exact top-200 ----------------
// Rewritten select: (a) AND/OR common-prefix skip deletes degenerate radix
// rounds (hi values share bytes 3,2); (b) early-exit the moment the
// candidate superset {vb >= partial T} fits in 256 (provable top-200
// superset); (c) shuffle suffix-scan (2 barriers vs 16); (d) rank-select
// (count-greater, broadcast LDS reads) replaces the 36-barrier bitonic.
// Exactness: partial T only ever selects a superset; rank over unique full
// keys (value desc, index asc via complement) reproduces the exact order.
__global__ __launch_bounds__(256) void topk_kernel(
    const ull* __restrict__ cand_hi,
    const ull* __restrict__ cand_lo,
    const int* __restrict__ cntl,
    const int* __restrict__ cnth,
    float* __restrict__ out,
    int capl)
{
    const int img = blockIdx.x;
    const int t = threadIdx.x;
    const int wv = t >> 6;
    const int lane = t & 63;
    __shared__ ull stage[NBANDS * CAPH];   // 32 KB: all hi keys fit
    __shared__ unsigned hist[4][256];      // wave-private histograms
    __shared__ unsigned sfx[256];
    __shared__ ull sel[256];
    __shared__ int s_ch[NBANDS], s_cl[NBANDS], s_oh[NBANDS + 1];
    __shared__ int s_ok;
    __shared__ int scnt;
    __shared__ unsigned s_pref;
    __shared__ int s_k, s_stop;
    __shared__ unsigned aW[4], oW[4], s_and, s_or, wsum[4];

    if (t == 0) { s_ok = 1; s_stop = 0; scnt = 0; }
    __syncthreads();
    if (t < NBANDS) {
        int raw = cnth[img * NBANDS + t];
        s_ch[t] = max(raw, 0);
        s_cl[t] = cntl[img * NBANDS + t];
        if (raw < 0) s_ok = 0;       // benign race: all writers store 0
    }
    __syncthreads();
    if (t == 0) {
        int a = 0;
        for (int b = 0; b < NBANDS; b++) { s_oh[b] = a; a += s_ch[b]; }
        s_oh[NBANDS] = a;
    }
    __syncthreads();
    const int nh = s_oh[NBANDS];
    const bool use_hi = (nh >= TOPK) && (s_ok != 0);

    if (use_hi) {
        int b = t >> 1, i0 = t & 1;              // 2 threads per band
        int nb = s_ch[b], ob = s_oh[b];
        const ull* p = cand_hi + (size_t)(img * NBANDS + b) * CAPH;
        for (int i = i0; i < nb; i += 2) stage[ob + i] = p[i];
    }
    __syncthreads();

    int n_tot = nh;
    if (!use_hi) {
        n_tot = 0;
        for (int b = 0; b < NBANDS; b++) n_tot += s_cl[b];
    }

    unsigned T = 0;   // value-bits threshold (partial or exact)
    if (n_tot > 256) {
        // ---- AND/OR over candidate value bits -> common high-byte prefix
        unsigned va = 0xFFFFFFFFu, vo = 0u;
        if (use_hi) {
            for (int i = t; i < nh; i += 256) {
                unsigned vb = (unsigned)(stage[i] >> 32);
                va &= vb; vo |= vb;
            }
        } else {
            for (int b = 0; b < NBANDS; b++) {
                int nb = s_cl[b];
                const ull* p = cand_lo + (size_t)(img * NBANDS + b) * capl;
                for (int i = t; i < nb; i += 256) {
                    unsigned vb = (unsigned)(p[i] >> 32);
                    va &= vb; vo |= vb;
                }
            }
        }
        #pragma unroll
        for (int off = 32; off > 0; off >>= 1) {
            va &= __shfl_xor(va, off);
            vo |= __shfl_xor(vo, off);
        }
        if (lane == 0) { aW[wv] = va; oW[wv] = vo; }
        __syncthreads();
        if (t == 0) {
            unsigned A = 0xFFFFFFFFu, O = 0u;
            for (int w = 0; w < 4; w++) { A &= aW[w]; O |= oW[w]; }
            s_and = A; s_or = O;
        }
        __syncthreads();
        const unsigned diff = s_and ^ s_or;
        int sb = 3;
        unsigned maskhi = 0u;
        while (sb >= 0 && ((diff >> (sb * 8)) & 0xFFu) == 0u) {
            maskhi |= 0xFFu << (sb * 8);
            sb--;
        }
        unsigned prefix = s_and & maskhi;

        if (sb < 0) {
            T = s_and;               // all candidate values identical
        } else {
            int kk = TOPK;
            for (int byte = sb; byte >= 0; byte--) {
                #pragma unroll
                for (int w = 0; w < 4; w++) hist[w][t] = 0;
                __syncthreads();
                const int shift = byte * 8;
                if (use_hi) {
                    for (int i = t; i < nh; i += 256) {
                        unsigned vb = (unsigned)(stage[i] >> 32);
                        if ((vb & maskhi) == prefix)
                            atomicAdd(&hist[wv][(vb >> shift) & 0xFFu], 1u);
                    }
                } else {
                    for (int b = 0; b < NBANDS; b++) {
                        int nb = s_cl[b];
                        const ull* p = cand_lo + (size_t)(img * NBANDS + b) * capl;
                        for (int i = t; i < nb; i += 256) {
                            unsigned vb = (unsigned)(p[i] >> 32);
                            if ((vb & maskhi) == prefix)
                                atomicAdd(&hist[wv][(vb >> shift) & 0xFFu], 1u);
                        }
                    }
                }
                __syncthreads();
                // suffix-scan of 256 bins: wave shuffle (2 barriers)
                unsigned v = hist[0][t] + hist[1][t] + hist[2][t] + hist[3][t];
                #pragma unroll
                for (int off = 1; off < 64; off <<= 1) {
                    unsigned u = __shfl_down(v, off);
                    if (lane + off < 64) v += u;
                }
                if (lane == 0) wsum[wv] = v;
                __syncthreads();
                unsigned add = 0;
                for (int w = wv + 1; w < 4; w++) add += wsum[w];
                unsigned myfx = v + add;         // count(matching, byte >= t)
                sfx[t] = myfx;
                __syncthreads();
                unsigned nxt = (t == 255) ? 0u : sfx[t + 1];
                if (myfx >= (unsigned)kk && nxt < (unsigned)kk) {
                    s_pref = prefix | ((unsigned)t << shift);
                    s_k = kk - (int)nxt;
                    // candidates {vb >= new partial T} = (TOPK-kk) + myfx
                    if ((TOPK - kk) + (int)myfx <= 256) s_stop = 1;
                }
                __syncthreads();
                prefix = s_pref;
                kk = s_k;
                maskhi |= (0xFFu << shift);
                if (s_stop) break;
            }
            T = prefix;
        }
    }

    __syncthreads();
    if (use_hi) {
        for (int i = t; i < nh; i += 256) {
            ull k = stage[i];
            if ((unsigned)(k >> 32) >= T) {
                int s = atomicAdd(&scnt, 1);
                if (s < 256) sel[s] = k;
            }
        }
    } else {
        for (int b = 0; b < NBANDS; b++) {
            int nb = s_cl[b];
            const ull* p = cand_lo + (size_t)(img * NBANDS + b) * capl;
            for (int i = t; i < nb; i += 256) {
                ull k = p[i];
                if ((unsigned)(k >> 32) >= T) {
                    int s = atomicAdd(&scnt, 1);
                    if (s < 256) sel[s] = k;
                }
            }
        }
    }
    __syncthreads();
    const int m = min(scnt, 256);
    ull* sorted = stage;               // stage is dead past this point
    if (t >= m) sel[t] = 0ull;
    sorted[t] = 0ull;
    __syncthreads();

    // ---- rank-select: exact descending order of unique full keys ----
    {
        ull k = sel[t];
        int rank = 0;
        for (int j = 0; j < 256; j++) rank += (sel[j] > k) ? 1 : 0;
        if (k != 0ull && rank < 256) sorted[rank] = k;
    }
    __syncthreads();

    // write: coords [NB,TOPK,2] then probs [NB,TOPK], all fp32
    if (t < TOPK) {
        ull key = sorted[t];
        float prob = 0.0f;
        unsigned row = 0, col = 0;
        if (key != 0ull) {
            prob = __uint_as_float((unsigned)(key >> 32));
            unsigned idx = 0xFFFFFFFFu - (unsigned)(key & 0xFFFFFFFFull);
            row = idx >> 10;
            col = idx & (W - 1);
        }
        size_t cbase = (size_t)img * TOPK * 2 + (size_t)t * 2;
        out[cbase + 0] = (float)row;
        out[cbase + 1] = (float)col;
        out[(size_t)NB * TOPK * 2 + (size_t)img * TOPK + t] = prob;
    }
}

extern "C" void kernel_launch(void* const* d_in, const int* in_sizes, int n_in,
                              void* d_out, int out_size, void* d_ws, size_t ws_size,
                              hipStream_t stream) {
    const float* center_map = (const float*)d_in[0];
    float* out = (float*)d_out;

    // workspace layout (all counts plain-stored by peak_kernel; no memset):
    //   [0, 16K)      : cntl[4096]
    //   [16K, 32K)    : cnth[4096]
    //   [32K, +1M)    : cand_hi[4096][CAPH]
    //   rest          : cand_lo[4096][capl]
    const int nbkt = NB * NBANDS;   // 4096
    int* cntl = (int*)d_ws;
    int* cnth = (int*)((char*)d_ws + 16384);
    ull* cand_hi = (ull*)((char*)d_ws + 32768);
    size_t hi_bytes = (size_t)nbkt * CAPH * sizeof(ull);   // 1 MB
    ull* cand_lo = (ull*)((char*)d_ws + 32768 + hi_bytes);
    size_t avail = (ws_size > 32768 + hi_bytes) ? (ws_size - 32768 - hi_bytes) : 0;
    int capl = (int)(avail / (nbkt * sizeof(ull)));
    if (capl > LBL) capl = LBL;
    if (capl < 1) capl = 1;

    dim3 gridA(NBANDS, NB);   // 128 x 32 = 4096 blocks
    peak_kernel<<<gridA, 256, 0, stream>>>(center_map, cand_hi, cand_lo,
                                           cntl, cnth, capl);

    topk_kernel<<<NB, 256, 0, stream>>>(cand_hi, cand_lo, cntl, cnth, out, capl);
}